// Round 2
// baseline (530.583 us; speedup 1.0000x reference)
//
#include <hip/hip_runtime.h>

// Rpool (R-MAC): x[16,2048,48,64] fp32 -> out[16,2048,1,1]
// Regions (verified vs reference, absmax 0.0 in R1):
//   global(48x64) + l1: (0,{0,16},48) + l2: ({0,16},{0,16,32},32)
//   + l3: ({0,12,24},{0,13,26,40},24) = 21 regions
// Row windows: W0=(0,48) W1=(0,32) W2=(16,48) W3=(0,24) W4=(12,36) W5=(24,48)
// Sub-blocks over k (row=4k+g): A=k0-2(r0-11) B=k3(r12-15) C=k4-5(r16-23)
//                               D=k6-7(r24-31) E=k8(r32-35) F=k9-11(r36-47)

#define BB 16
#define CC 2048
#define HH 48
#define WW 64
#define NREG 21
#define NWIN 6

__constant__ int c_reg_win[NREG] = {0, 0,0, 1,1,1, 2,2,2, 3,3,3,3, 4,4,4,4, 5,5,5,5};
__constant__ int c_reg_j[NREG]   = {0, 0,16, 0,16,32, 0,16,32, 0,13,26,40, 0,13,26,40, 0,13,26,40};
__constant__ int c_reg_wl[NREG]  = {64, 48,48, 32,32,32, 32,32,32, 24,24,24,24, 24,24,24,24, 24,24,24,24};

__device__ __forceinline__ float4 max4(float4 a, float4 b) {
    return make_float4(fmaxf(a.x, b.x), fmaxf(a.y, b.y), fmaxf(a.z, b.z), fmaxf(a.w, b.w));
}
__device__ __forceinline__ float4 bfly4(float4 a, int m) {
    a.x = fmaxf(a.x, __shfl_xor(a.x, m));
    a.y = fmaxf(a.y, __shfl_xor(a.y, m));
    a.z = fmaxf(a.z, __shfl_xor(a.z, m));
    a.w = fmaxf(a.w, __shfl_xor(a.w, m));
    return a;
}

// Stage 1: ONE WAVE per (b,c) map. 4 maps per 256-thread block.
__global__ __launch_bounds__(256) void rpool_stage1(const float* __restrict__ x,
                                                    float* __restrict__ R) {
    __shared__ float cm[4][NWIN * WW];     // per-wave colmax table, 6 KB total

    const int wave = threadIdx.x >> 6;
    const int lane = threadIdx.x & 63;
    const int map  = (blockIdx.x << 2) + wave;   // b*C + c
    const int q    = lane & 15;

    // ---- load full 48x64 map: 12 float4 per lane, coalesced 1KB/instr ----
    const float4* __restrict__ src = (const float4*)(x + (size_t)map * (HH * WW));
    float4 v[12];
    #pragma unroll
    for (int k = 0; k < 12; ++k) v[k] = src[(k << 6) + lane];

    // ---- hierarchical sub-block maxes (wave-uniform membership) ----
    float4 A  = max4(max4(v[0], v[1]), v[2]);
    float4 Bs = v[3];
    float4 Cs = max4(v[4], v[5]);
    float4 Ds = max4(v[6], v[7]);
    float4 Es = v[8];
    float4 Fs = max4(max4(v[9], v[10]), v[11]);

    float4 w3 = max4(max4(A, Bs), Cs);       // rows 0-23
    float4 w1 = max4(w3, Ds);                // rows 0-31
    float4 EF = max4(Es, Fs);
    float4 w5 = max4(Ds, EF);                // rows 24-47
    float4 w0 = max4(w3, w5);                // rows 0-47
    float4 w2 = max4(Cs, w5);                // rows 16-47
    float4 w4 = max4(max4(Bs, Cs), max4(Ds, Es)); // rows 12-35

    // ---- reduce the 4 row-groups (lane bit4,bit5) via shuffle butterfly ----
    w0 = bfly4(bfly4(w0, 16), 32);
    w1 = bfly4(bfly4(w1, 16), 32);
    w2 = bfly4(bfly4(w2, 16), 32);
    w3 = bfly4(bfly4(w3, 16), 32);
    w4 = bfly4(bfly4(w4, 16), 32);
    w5 = bfly4(bfly4(w5, 16), 32);

    if (lane < 16) {
        float4* dst = (float4*)cm[wave];
        dst[0 * 16 + q] = w0;
        dst[1 * 16 + q] = w1;
        dst[2 * 16 + q] = w2;
        dst[3 * 16 + q] = w3;
        dst[4 * 16 + q] = w4;
        dst[5 * 16 + q] = w5;
    }
    __syncthreads();   // cheap: guarantees LDS visibility for the scan

    // ---- 21 region maxes, 2 lanes per region (<=32 serial steps) ----
    if (lane < 42) {
        const int r   = (lane < 21) ? lane : (lane - 21);
        const int win = c_reg_win[r];
        const int j   = c_reg_j[r];
        const int wl  = c_reg_wl[r];
        const int h   = wl >> 1;
        const int k0  = (lane < 21) ? 0 : h;
        const int k1  = (lane < 21) ? h : wl;
        const float* p = cm[wave] + win * WW + j;
        float m = p[k0];
        for (int k = k0 + 1; k < k1; ++k) m = fmaxf(m, p[k]);
        float other = __shfl(m, lane + 21);  // lanes 0-20 pull second half
        if (lane < 21) {
            m = fmaxf(m, other);
            const int b = map >> 11;
            const int c = map & (CC - 1);
            R[(((size_t)b * NREG + r) << 11) + c] = m;
        }
    }
}

// Stage 2: one 1024-thread block per batch. L2-norms + region sum + final norm.
__global__ __launch_bounds__(1024) void rpool_stage2(const float* __restrict__ R,
                                                     float* __restrict__ out) {
    const int b = blockIdx.x;
    const int t = threadIdx.x;
    const int lane = t & 63;
    const int wave = t >> 6;               // 0..15

    __shared__ float partials[NREG][16];
    __shared__ float scale[NREG];
    __shared__ float osq_part[16];

    const float* __restrict__ Rb = R + (size_t)b * NREG * CC;

    // per-region sum of squares over channels
    #pragma unroll
    for (int r = 0; r < NREG; ++r) {
        float v0 = Rb[r * CC + t];
        float v1 = Rb[r * CC + t + 1024];
        float acc = v0 * v0 + v1 * v1;
        #pragma unroll
        for (int off = 32; off; off >>= 1) acc += __shfl_down(acc, off);
        if (lane == 0) partials[r][wave] = acc;
    }
    __syncthreads();
    if (t < NREG) {
        float s = 0.f;
        #pragma unroll
        for (int wv = 0; wv < 16; ++wv) s += partials[t][wv];
        scale[t] = 1.0f / (sqrtf(s) + 1e-6f);
    }
    __syncthreads();

    // normalized sum over regions + final norm
    float s0 = 0.f, s1 = 0.f;
    #pragma unroll
    for (int r = 0; r < NREG; ++r) {
        s0 += Rb[r * CC + t] * scale[r];
        s1 += Rb[r * CC + t + 1024] * scale[r];
    }
    float osq = s0 * s0 + s1 * s1;
    #pragma unroll
    for (int off = 32; off; off >>= 1) osq += __shfl_down(osq, off);
    if (lane == 0) osq_part[wave] = osq;
    __syncthreads();
    float tot = 0.f;
    #pragma unroll
    for (int wv = 0; wv < 16; ++wv) tot += osq_part[wv];
    const float oscale = 1.0f / (sqrtf(tot) + 1e-6f);
    out[(size_t)b * CC + t]        = s0 * oscale;
    out[(size_t)b * CC + t + 1024] = s1 * oscale;
}

extern "C" void kernel_launch(void* const* d_in, const int* in_sizes, int n_in,
                              void* d_out, int out_size, void* d_ws, size_t ws_size,
                              hipStream_t stream) {
    const float* x = (const float*)d_in[0];
    float* R = (float*)d_ws;               // [16][21][2048] = 2.75 MB scratch
    float* out = (float*)d_out;

    rpool_stage1<<<(BB * CC) / 4, 256, 0, stream>>>(x, R);
    rpool_stage2<<<BB, 1024, 0, stream>>>(R, out);
}